// Round 1
// baseline (1080.472 us; speedup 1.0000x reference)
//
#include <hip/hip_runtime.h>
#include <hip/hip_bf16.h>

#define NN 500000
#define NE 1250000
#define NF 128
#define NH 64
#define NC 10
#define NG 512
#define ELLW 8

typedef __attribute__((ext_vector_type(8))) short short8;
typedef __attribute__((ext_vector_type(4))) float floatx4;

__device__ __forceinline__ unsigned short f2bf(float f) {
  unsigned u = __builtin_bit_cast(unsigned, f);
  u += 0x7FFFu + ((u >> 16) & 1u);
  return (unsigned short)(u >> 16);
}
__device__ __forceinline__ float bf2f(unsigned short u) {
  return __builtin_bit_cast(float, (unsigned)u << 16);
}
__device__ __forceinline__ float asf(int i) { return __builtin_bit_cast(float, i); }

// merged prep: zero deg/cur/counter/pool-accumulators + transpose-convert all three weights
__global__ __launch_bounds__(256) void k_init(int* __restrict__ deg, int* __restrict__ cur,
                                              int* __restrict__ counter,
                                              float* __restrict__ gsum, int* __restrict__ gmax,
                                              int* __restrict__ gcnt,
                                              const float* __restrict__ W0,
                                              const float* __restrict__ W1,
                                              const float* __restrict__ W2,
                                              unsigned short* __restrict__ Wt0,
                                              unsigned short* __restrict__ Wt1,
                                              unsigned short* __restrict__ Wt2) {
  int i = blockIdx.x * 256 + threadIdx.x;
  if (i < NN) { deg[i] = 0; cur[i] = 0; }
  if (i == 0) *counter = 0;
  if (i < NG * 64) { gsum[i] = 0.f; gmax[i] = 0; }
  if (i < NG) gcnt[i] = 0;
  if (i < NF * 64) { int k = i / 64, n = i % 64; Wt0[n * NF + k] = f2bf(W0[i]); }
  if (i < 64 * 64) {
    int k = i / 64, n = i % 64;
    Wt1[n * 64 + k] = f2bf(W1[i]);
    Wt2[n * 64 + k] = f2bf(W2[i]);
  }
}

__global__ __launch_bounds__(256) void k_deg(const int* __restrict__ dst, int* __restrict__ deg) {
  int e = blockIdx.x * 256 + threadIdx.x;
  if (e < NE) atomicAdd(&deg[dst[e]], 1);
}

__global__ __launch_bounds__(256) void k_dinv(const int* __restrict__ deg,
                                              float* __restrict__ dinv,
                                              int* __restrict__ odeg) {
  int i = blockIdx.x * 256 + threadIdx.x;
  if (i < NN) {
    int d = deg[i];
    dinv[i] = rsqrtf((float)(d + 1));
    odeg[i] = d > ELLW ? d - ELLW : 0;
  }
}

// overflow CSR row starts: wave-scan, one atomic per wave (row order arbitrary)
__global__ __launch_bounds__(256) void k_rowstart(const int* __restrict__ deg,
                                                  int* __restrict__ row_start,
                                                  int* __restrict__ counter) {
  int i = blockIdx.x * 256 + threadIdx.x;
  int lane = threadIdx.x & 63;
  int d = (i < NN) ? deg[i] : 0;
  int incl = d;
#pragma unroll
  for (int off = 1; off < 64; off <<= 1) {
    int n = __shfl_up(incl, off, 64);
    if (lane >= off) incl += n;
  }
  int total = __shfl(incl, 63, 64);
  int base = 0;
  if (lane == 63) base = atomicAdd(counter, total);
  base = __shfl(base, 63, 64);
  if (i < NN) row_start[i] = base + incl - d;
}

// Bucket-fill: slot<ELLW -> ELL row, else overflow CSR. ELL is NOT pre-initialized:
// consumers guard every slot by degree (cndmask to (self, 0)).
__global__ __launch_bounds__(256) void k_fill(const int* __restrict__ ei,
                                              const float* __restrict__ dinv,
                                              int* __restrict__ cur,
                                              int2* __restrict__ ell,
                                              const int* __restrict__ ostart,
                                              int2* __restrict__ ovf) {
  int e = blockIdx.x * 256 + threadIdx.x;
  if (e >= NE) return;
  int s = ei[e];
  int d = ei[NE + e];
  float nrm = dinv[s] * dinv[d];
  int slot = atomicAdd(&cur[d], 1);
  int2 v;
  v.x = s;
  v.y = __builtin_bit_cast(int, nrm);
  if (slot < ELLW) ell[(size_t)d * ELLW + slot] = v;
  else ovf[ostart[d] + slot - ELLW] = v;
}

// Layer-1 GEMM: lin[M,64](bf16) = x[M,128](f32) @ W
__global__ __launch_bounds__(256) void k_gemm_f32(const float* __restrict__ Ain,
                                                  const unsigned short* __restrict__ Wt,
                                                  unsigned short* __restrict__ linbf) {
  constexpr int K = 128, KC = 4, SP = K + 8;
  __shared__ unsigned short Wl[64 * SP];
  int tid = threadIdx.x;
  for (int idx = tid * 8; idx < 64 * K; idx += 2048) {
    int n = idx / K, k = idx % K;
    *(short8*)&Wl[n * SP + k] = *(const short8*)&Wt[idx];
  }
  __syncthreads();

  int lane = tid & 63, wave = tid >> 6;
  int quad = lane >> 4, l16 = lane & 15;

  short8 bfrag[4][KC];
#pragma unroll
  for (int nt = 0; nt < 4; ++nt)
#pragma unroll
    for (int kc = 0; kc < KC; ++kc)
      bfrag[nt][kc] = *(const short8*)&Wl[(nt * 16 + l16) * SP + kc * 32 + quad * 8];

  const int ntiles = NN / 16;  // 31250
  for (int t0 = (blockIdx.x * 4 + wave) * 2; t0 < ntiles; t0 += gridDim.x * 8) {
    floatx4 acc[2][4];
    floatx4 araw[2][KC][2];
#pragma unroll
    for (int tt = 0; tt < 2; ++tt) {
      int arow = (t0 + tt) * 16 + l16;
      const float* Ab = Ain + (size_t)arow * K + quad * 8;
#pragma unroll
      for (int kc = 0; kc < KC; ++kc) {
        araw[tt][kc][0] = *(const floatx4*)(Ab + kc * 32);
        araw[tt][kc][1] = *(const floatx4*)(Ab + kc * 32 + 4);
      }
    }
#pragma unroll
    for (int tt = 0; tt < 2; ++tt) {
      floatx4 z = {0.f, 0.f, 0.f, 0.f};
#pragma unroll
      for (int nt = 0; nt < 4; ++nt) acc[tt][nt] = z;
#pragma unroll
      for (int kc = 0; kc < KC; ++kc) {
        short8 af;
#pragma unroll
        for (int q = 0; q < 4; ++q) {
          af[q] = (short)f2bf(araw[tt][kc][0][q]);
          af[q + 4] = (short)f2bf(araw[tt][kc][1][q]);
        }
#pragma unroll
        for (int nt = 0; nt < 4; ++nt)
          acc[tt][nt] = __builtin_amdgcn_mfma_f32_16x16x32_bf16(af, bfrag[nt][kc], acc[tt][nt], 0, 0, 0);
      }
#pragma unroll
      for (int i = 0; i < 4; ++i) {
        int r = (t0 + tt) * 16 + quad * 4 + i;
        unsigned short* lp = linbf + (size_t)r * 64 + l16;
#pragma unroll
        for (int nt = 0; nt < 4; ++nt) lp[nt * 16] = f2bf(acc[tt][nt][i]);
      }
    }
  }
}

// Layer-1 aggregation (no matvec): h1 = relu(agg(lin1) + b0) -> bf16
// ELL slots guarded by degree (no pad init needed).
__global__ __launch_bounds__(256) void k_agg(const unsigned short* __restrict__ linbf,
                                             const float* __restrict__ dinv,
                                             const float* __restrict__ bias,
                                             const int* __restrict__ deg,
                                             const int2* __restrict__ ell,
                                             const int* __restrict__ ostart,
                                             const int2* __restrict__ ovf,
                                             unsigned short* __restrict__ hout) {
  int r = blockIdx.x * 4 + (threadIdx.x >> 6);
  if (r >= NN) return;
  int c = threadIdx.x & 63;
  const int4* ellv = (const int4*)(ell + (size_t)r * ELLW);
  int dg = deg[r];
  float dv = dinv[r];
  float bc = bias[c];
  float acc = bf2f(linbf[(size_t)r * 64 + c]) * dv * dv;

  int4 q0 = ellv[0], q1 = ellv[1];
  float n0 = dg > 0 ? asf(q0.y) : 0.f; int s0 = dg > 0 ? q0.x : r;
  float n1 = dg > 1 ? asf(q0.w) : 0.f; int s1 = dg > 1 ? q0.z : r;
  float n2 = dg > 2 ? asf(q1.y) : 0.f; int s2 = dg > 2 ? q1.x : r;
  float n3 = dg > 3 ? asf(q1.w) : 0.f; int s3 = dg > 3 ? q1.z : r;
  acc = fmaf(n0, bf2f(linbf[(size_t)s0 * 64 + c]), acc);
  acc = fmaf(n1, bf2f(linbf[(size_t)s1 * 64 + c]), acc);
  acc = fmaf(n2, bf2f(linbf[(size_t)s2 * 64 + c]), acc);
  acc = fmaf(n3, bf2f(linbf[(size_t)s3 * 64 + c]), acc);
  if (dg > 4) {
    int4 q2 = ellv[2], q3 = ellv[3];
    float n4 = asf(q2.y);                int s4 = q2.x;
    float n5 = dg > 5 ? asf(q2.w) : 0.f; int s5 = dg > 5 ? q2.z : r;
    float n6 = dg > 6 ? asf(q3.y) : 0.f; int s6 = dg > 6 ? q3.x : r;
    float n7 = dg > 7 ? asf(q3.w) : 0.f; int s7 = dg > 7 ? q3.z : r;
    acc = fmaf(n4, bf2f(linbf[(size_t)s4 * 64 + c]), acc);
    acc = fmaf(n5, bf2f(linbf[(size_t)s5 * 64 + c]), acc);
    acc = fmaf(n6, bf2f(linbf[(size_t)s6 * 64 + c]), acc);
    acc = fmaf(n7, bf2f(linbf[(size_t)s7 * 64 + c]), acc);
  }
  if (dg > ELLW) {
    int rs = ostart[r];
    int on = dg - ELLW;
    for (int j = 0; j < on; j += 4) {
      int2 e0 = ovf[rs + j];
      int2 e1 = ovf[rs + j + 1];
      int2 e2 = ovf[rs + j + 2];
      int2 e3 = ovf[rs + j + 3];
      int rem = on - j;
      float m0 = asf(e0.y);
      float m1 = rem > 1 ? asf(e1.y) : 0.f;
      float m2 = rem > 2 ? asf(e2.y) : 0.f;
      float m3 = rem > 3 ? asf(e3.y) : 0.f;
      int t0 = e0.x;
      int t1 = rem > 1 ? e1.x : r;
      int t2 = rem > 2 ? e2.x : r;
      int t3 = rem > 3 ? e3.x : r;
      acc = fmaf(m0, bf2f(linbf[(size_t)t0 * 64 + c]), acc);
      acc = fmaf(m1, bf2f(linbf[(size_t)t1 * 64 + c]), acc);
      acc = fmaf(m2, bf2f(linbf[(size_t)t2 * 64 + c]), acc);
      acc = fmaf(m3, bf2f(linbf[(size_t)t3 * 64 + c]), acc);
    }
  }
  hout[(size_t)r * 64 + c] = f2bf(fmaxf(acc + bc, 0.f));
}

// Fused layer 2/3: hout = relu( agg(hin) @ W + bias ), using agg(h@W) = agg(h)@W.
// POOL=1 (layer 3): skip the H write entirely; block-reduce mean/max per graph
// segment (batch is sorted) in LDS and emit one atomicAdd/atomicMax per (g,feat).
template <int POOL>
__global__ __launch_bounds__(256) void k_layer(const unsigned short* __restrict__ hin,
                                               const float* __restrict__ dinv,
                                               const float* __restrict__ bias,
                                               const int* __restrict__ deg,
                                               const int2* __restrict__ ell,
                                               const int* __restrict__ ostart,
                                               const int2* __restrict__ ovf,
                                               const unsigned short* __restrict__ Wt,  // [n][k] bf16 64x64
                                               unsigned short* __restrict__ hout,
                                               float* __restrict__ gsum,
                                               int* __restrict__ gmax,
                                               int* __restrict__ gcnt,
                                               const int* __restrict__ batch) {
  constexpr int SP = 72;                 // bf16 LDS row stride (phase 1/2 view)
  __shared__ float smemf[64 * 66];       // 16.9 KB; aliased as ushort Sl; POOL reuses as f32 P[64][66]
  unsigned short* Sl = (unsigned short*)smemf;
  int tid = threadIdx.x;
  int lane = tid & 63, wave = tid >> 6, quad = lane >> 4, l16 = lane & 15;

  // stage W flat -> B-frags in regs
  for (int idx = tid * 8; idx < 64 * 64; idx += 2048)
    *(short8*)&Sl[idx] = *(const short8*)&Wt[idx];
  __syncthreads();
  short8 bfrag[4][2];
#pragma unroll
  for (int nt = 0; nt < 4; ++nt)
#pragma unroll
    for (int kc = 0; kc < 2; ++kc)
      bfrag[nt][kc] = *(const short8*)&Sl[(nt * 16 + l16) * 64 + kc * 32 + quad * 8];
  float bb[4];
#pragma unroll
  for (int nt = 0; nt < 4; ++nt) bb[nt] = bias[nt * 16 + l16];
  __syncthreads();  // all waves done reading W before phase 1 overwrites Sl

  int base = blockIdx.x * 64;
  int rbase = base + wave * 16;

  // phase 1: aggregate 16 nodes (wave-wide, lane = feature)
#pragma unroll 4
  for (int j = 0; j < 16; ++j) {
    int r = rbase + j;
    float acc = 0.f;
    if (r < NN) {
      const int4* ellv = (const int4*)(ell + (size_t)r * ELLW);
      int dg = deg[r];
      float dv = dinv[r];
      acc = bf2f(hin[(size_t)r * 64 + lane]) * dv * dv;
      int4 q0 = ellv[0], q1 = ellv[1];
      float n0 = dg > 0 ? asf(q0.y) : 0.f; int s0 = dg > 0 ? q0.x : r;
      float n1 = dg > 1 ? asf(q0.w) : 0.f; int s1 = dg > 1 ? q0.z : r;
      float n2 = dg > 2 ? asf(q1.y) : 0.f; int s2 = dg > 2 ? q1.x : r;
      float n3 = dg > 3 ? asf(q1.w) : 0.f; int s3 = dg > 3 ? q1.z : r;
      acc = fmaf(n0, bf2f(hin[(size_t)s0 * 64 + lane]), acc);
      acc = fmaf(n1, bf2f(hin[(size_t)s1 * 64 + lane]), acc);
      acc = fmaf(n2, bf2f(hin[(size_t)s2 * 64 + lane]), acc);
      acc = fmaf(n3, bf2f(hin[(size_t)s3 * 64 + lane]), acc);
      if (dg > 4) {
        int4 q2 = ellv[2], q3 = ellv[3];
        float n4 = asf(q2.y);                int s4 = q2.x;
        float n5 = dg > 5 ? asf(q2.w) : 0.f; int s5 = dg > 5 ? q2.z : r;
        float n6 = dg > 6 ? asf(q3.y) : 0.f; int s6 = dg > 6 ? q3.x : r;
        float n7 = dg > 7 ? asf(q3.w) : 0.f; int s7 = dg > 7 ? q3.z : r;
        acc = fmaf(n4, bf2f(hin[(size_t)s4 * 64 + lane]), acc);
        acc = fmaf(n5, bf2f(hin[(size_t)s5 * 64 + lane]), acc);
        acc = fmaf(n6, bf2f(hin[(size_t)s6 * 64 + lane]), acc);
        acc = fmaf(n7, bf2f(hin[(size_t)s7 * 64 + lane]), acc);
      }
      if (dg > ELLW) {
        int rs = ostart[r];
        int on = dg - ELLW;
        for (int jj = 0; jj < on; jj += 4) {
          int2 e0 = ovf[rs + jj];
          int2 e1 = ovf[rs + jj + 1];
          int2 e2 = ovf[rs + jj + 2];
          int2 e3 = ovf[rs + jj + 3];
          int rem = on - jj;
          float m0 = asf(e0.y);
          float m1 = rem > 1 ? asf(e1.y) : 0.f;
          float m2 = rem > 2 ? asf(e2.y) : 0.f;
          float m3 = rem > 3 ? asf(e3.y) : 0.f;
          int t0 = e0.x;
          int t1 = rem > 1 ? e1.x : r;
          int t2 = rem > 2 ? e2.x : r;
          int t3 = rem > 3 ? e3.x : r;
          acc = fmaf(m0, bf2f(hin[(size_t)t0 * 64 + lane]), acc);
          acc = fmaf(m1, bf2f(hin[(size_t)t1 * 64 + lane]), acc);
          acc = fmaf(m2, bf2f(hin[(size_t)t2 * 64 + lane]), acc);
          acc = fmaf(m3, bf2f(hin[(size_t)t3 * 64 + lane]), acc);
        }
      }
    }
    Sl[(wave * 16 + j) * SP + lane] = f2bf(acc);
  }

  // phase 2: s @ W  (wave reads only its own 16 rows -> no barrier needed)
  floatx4 z = {0.f, 0.f, 0.f, 0.f};
  floatx4 acc4[4] = {z, z, z, z};
#pragma unroll
  for (int kc = 0; kc < 2; ++kc) {
    short8 af = *(const short8*)&Sl[(wave * 16 + l16) * SP + kc * 32 + quad * 8];
#pragma unroll
    for (int nt = 0; nt < 4; ++nt)
      acc4[nt] = __builtin_amdgcn_mfma_f32_16x16x32_bf16(af, bfrag[nt][kc], acc4[nt], 0, 0, 0);
  }

  if constexpr (!POOL) {
#pragma unroll
    for (int i = 0; i < 4; ++i) {
      int r = rbase + quad * 4 + i;
      if (r < NN) {
        unsigned short* hp = hout + (size_t)r * 64 + l16;
#pragma unroll
        for (int nt = 0; nt < 4; ++nt)
          hp[nt * 16] = f2bf(fmaxf(acc4[nt][i] + bb[nt], 0.f));
      }
    }
  } else {
    // -------- fused global mean/max pool (layer-3 output never touches HBM) --------
    __shared__ int sb[64];
    __shared__ float reds[256];
    __shared__ float redm[256];
    __shared__ int redc[4];
    __syncthreads();  // all waves done reading their Sl rows before P overwrite
#pragma unroll
    for (int i = 0; i < 4; ++i) {
      int row = wave * 16 + quad * 4 + i;
#pragma unroll
      for (int nt = 0; nt < 4; ++nt)
        smemf[row * 66 + nt * 16 + l16] = fmaxf(acc4[nt][i] + bb[nt], 0.f);
    }
    if (tid < 64) sb[tid] = (base + tid < NN) ? batch[base + tid] : 0x7fffffff;
    __syncthreads();
    int nvalid = NN - base; if (nvalid > 64) nvalid = 64;
    int gs = sb[0], ge = sb[nvalid - 1];
    int feat = tid & 63, strip = tid >> 6;
    for (int g = gs; g <= ge; ++g) {   // uniform trip count across block (usually 1)
      float s = 0.f, m = 0.f;
      int cl = 0;
#pragma unroll
      for (int j = 0; j < 16; ++j) {
        int row = strip * 16 + j;
        float v = smemf[row * 66 + feat];
        if (sb[row] == g) { s += v; m = fmaxf(m, v); cl++; }
      }
      reds[tid] = s;
      redm[tid] = m;
      if (feat == 0) redc[strip] = cl;
      __syncthreads();
      if (strip == 0) {
        s += reds[64 + feat] + reds[128 + feat] + reds[192 + feat];
        m = fmaxf(fmaxf(m, redm[64 + feat]), fmaxf(redm[128 + feat], redm[192 + feat]));
        atomicAdd(&gsum[g * 64 + feat], s);
        atomicMax(&gmax[g * 64 + feat], __builtin_bit_cast(int, m));  // v>=0: int order == float order
        if (feat == 0) atomicAdd(&gcnt[g], redc[0] + redc[1] + redc[2] + redc[3]);
      }
      __syncthreads();
    }
  }
}

__global__ __launch_bounds__(128) void k_head(const float* __restrict__ gsum,
                                              const int* __restrict__ gmax,
                                              const int* __restrict__ gcnt,
                                              const float* __restrict__ Wout,
                                              const float* __restrict__ bout,
                                              float* __restrict__ out) {
  __shared__ float p[128];
  int g = blockIdx.x, tid = threadIdx.x;
  if (tid < 64) {
    int c = gcnt[g];
    float inv = c > 0 ? 1.0f / (float)c : 0.f;  // empty graph: sum==0 -> mean 0 matches ref
    p[tid] = gsum[g * 64 + tid] * inv;
    p[64 + tid] = asf(gmax[g * 64 + tid]);      // init 0 matches ref's neginf->0 guard
  }
  __syncthreads();
  if (tid < NC) {
    float acc = bout[tid];
#pragma unroll 8
    for (int c2 = 0; c2 < 128; ++c2) acc += p[c2] * Wout[c2 * NC + tid];
    out[g * NC + tid] = acc;
  }
}

extern "C" void kernel_launch(void* const* d_in, const int* in_sizes, int n_in,
                              void* d_out, int out_size, void* d_ws, size_t ws_size,
                              hipStream_t stream) {
  const float* x     = (const float*)d_in[0];
  const int*   ei    = (const int*)d_in[1];
  const int*   batch = (const int*)d_in[2];
  const float* W0    = (const float*)d_in[3];
  const float* b0    = (const float*)d_in[4];
  const float* W1    = (const float*)d_in[5];
  const float* b1    = (const float*)d_in[6];
  const float* W2    = (const float*)d_in[7];
  const float* b2    = (const float*)d_in[8];
  const float* Wout  = (const float*)d_in[9];
  const float* bout  = (const float*)d_in[10];
  float* out = (float*)d_out;

  char* ws = (char*)d_ws;
  size_t off = 0;
  auto alloc = [&](size_t bytes) -> void* {
    void* p = ws + off;
    off = (off + bytes + 255) & ~(size_t)255;
    return p;
  };
  int*   deg     = (int*)alloc((size_t)NN * 4);
  int*   odeg    = (int*)alloc((size_t)NN * 4);
  int*   counter = (int*)alloc(4);
  float* dinv    = (float*)alloc((size_t)NN * 4);
  int*   ostart  = (int*)alloc((size_t)NN * 4);
  int*   cur     = (int*)alloc((size_t)NN * 4);
  int2*  ell     = (int2*)alloc((size_t)NN * ELLW * 8);   // 32 MB, NOT pre-initialized
  int2*  ovf     = (int2*)alloc(((size_t)NE + 4) * 8);
  unsigned short* linbf = (unsigned short*)alloc((size_t)NN * 64 * 2);
  unsigned short* H1    = (unsigned short*)alloc((size_t)NN * 64 * 2);
  unsigned short* H2    = (unsigned short*)alloc((size_t)NN * 64 * 2);
  unsigned short* Wt0 = (unsigned short*)alloc(64 * 128 * 2);
  unsigned short* Wt1 = (unsigned short*)alloc(64 * 64 * 2);
  unsigned short* Wt2 = (unsigned short*)alloc(64 * 64 * 2);
  float* gsum = (float*)alloc((size_t)NG * 64 * 4);
  int*   gmax = (int*)alloc((size_t)NG * 64 * 4);
  int*   gcnt = (int*)alloc((size_t)NG * 4);

  // graph prep (merged: zero-init + weight transpose in one launch)
  k_init<<<(NN + 255) / 256, 256, 0, stream>>>(deg, cur, counter, gsum, gmax, gcnt,
                                               W0, W1, W2, Wt0, Wt1, Wt2);
  k_deg<<<(NE + 255) / 256, 256, 0, stream>>>(ei + NE, deg);
  k_dinv<<<(NN + 255) / 256, 256, 0, stream>>>(deg, dinv, odeg);
  k_rowstart<<<(NN + 255) / 256, 256, 0, stream>>>(odeg, ostart, counter);
  k_fill<<<(NE + 255) / 256, 256, 0, stream>>>(ei, dinv, cur, ell, ostart, ovf);

  // layer 1: transform-first (x is 128-wide; cheaper to shrink before gathering)
  k_gemm_f32<<<2048, 256, 0, stream>>>(x, Wt0, linbf);
  k_agg<<<(NN + 3) / 4, 256, 0, stream>>>(linbf, dinv, b0, deg, ell, ostart, ovf, H1);
  // layer 2: aggregate-first fused (agg(h)@W + b, relu)
  k_layer<0><<<(NN + 63) / 64, 256, 0, stream>>>(H1, dinv, b1, deg, ell, ostart, ovf, Wt1, H2,
                                                 nullptr, nullptr, nullptr, nullptr);
  // layer 3 + fused mean/max pool (no H3 buffer, no k_pool pass)
  k_layer<1><<<(NN + 63) / 64, 256, 0, stream>>>(H2, dinv, b2, deg, ell, ostart, ovf, Wt2, nullptr,
                                                 gsum, gmax, gcnt, batch);
  k_head<<<NG, 128, 0, stream>>>(gsum, gmax, gcnt, Wout, bout, out);
}

// Round 2
// 958.349 us; speedup vs baseline: 1.1274x; 1.1274x over previous
//
#include <hip/hip_runtime.h>
#include <hip/hip_bf16.h>

#define NN 500000
#define NE 1250000
#define NF 128
#define NH 64
#define NC 10
#define NG 512
#define ELLW 8

typedef __attribute__((ext_vector_type(8))) short short8;
typedef __attribute__((ext_vector_type(4))) float floatx4;

__device__ __forceinline__ unsigned short f2bf(float f) {
  unsigned u = __builtin_bit_cast(unsigned, f);
  u += 0x7FFFu + ((u >> 16) & 1u);
  return (unsigned short)(u >> 16);
}
__device__ __forceinline__ float bf2f(unsigned short u) {
  return __builtin_bit_cast(float, (unsigned)u << 16);
}
__device__ __forceinline__ float asf(int i) { return __builtin_bit_cast(float, i); }

// merged prep: zero deg/cur/counter/pool-accumulators, pad-init ELL to (self,0),
// transpose-convert all three weights. ELL pad makes gather loads unconditional
// (round-1 lesson: degree-guarded addresses serialize the latency-bound gather).
__global__ __launch_bounds__(256) void k_init(int* __restrict__ deg, int* __restrict__ cur,
                                              int* __restrict__ counter,
                                              float* __restrict__ gsum, int* __restrict__ gmax,
                                              int* __restrict__ gcnt,
                                              int4* __restrict__ ell4,
                                              const float* __restrict__ W0,
                                              const float* __restrict__ W1,
                                              const float* __restrict__ W2,
                                              unsigned short* __restrict__ Wt0,
                                              unsigned short* __restrict__ Wt1,
                                              unsigned short* __restrict__ Wt2) {
  int i = blockIdx.x * 256 + threadIdx.x;
  if (i < NN) {
    deg[i] = 0; cur[i] = 0;
    int4 p; p.x = i; p.y = 0; p.z = i; p.w = 0;   // two (self, 0) ELL entries
    ell4[(size_t)i * 4 + 0] = p;
    ell4[(size_t)i * 4 + 1] = p;
    ell4[(size_t)i * 4 + 2] = p;
    ell4[(size_t)i * 4 + 3] = p;
  }
  if (i == 0) *counter = 0;
  if (i < NG * 64) { gsum[i] = 0.f; gmax[i] = 0; }
  if (i < NG) gcnt[i] = 0;
  if (i < NF * 64) { int k = i / 64, n = i % 64; Wt0[n * NF + k] = f2bf(W0[i]); }
  if (i < 64 * 64) {
    int k = i / 64, n = i % 64;
    Wt1[n * 64 + k] = f2bf(W1[i]);
    Wt2[n * 64 + k] = f2bf(W2[i]);
  }
}

__global__ __launch_bounds__(256) void k_deg(const int* __restrict__ dst, int* __restrict__ deg) {
  int e = blockIdx.x * 256 + threadIdx.x;
  if (e < NE) atomicAdd(&deg[dst[e]], 1);
}

__global__ __launch_bounds__(256) void k_dinv(const int* __restrict__ deg,
                                              float* __restrict__ dinv,
                                              int* __restrict__ odeg) {
  int i = blockIdx.x * 256 + threadIdx.x;
  if (i < NN) {
    int d = deg[i];
    dinv[i] = rsqrtf((float)(d + 1));
    odeg[i] = d > ELLW ? d - ELLW : 0;
  }
}

// overflow CSR row starts: wave-scan, one atomic per wave (row order arbitrary)
__global__ __launch_bounds__(256) void k_rowstart(const int* __restrict__ deg,
                                                  int* __restrict__ row_start,
                                                  int* __restrict__ counter) {
  int i = blockIdx.x * 256 + threadIdx.x;
  int lane = threadIdx.x & 63;
  int d = (i < NN) ? deg[i] : 0;
  int incl = d;
#pragma unroll
  for (int off = 1; off < 64; off <<= 1) {
    int n = __shfl_up(incl, off, 64);
    if (lane >= off) incl += n;
  }
  int total = __shfl(incl, 63, 64);
  int base = 0;
  if (lane == 63) base = atomicAdd(counter, total);
  base = __shfl(base, 63, 64);
  if (i < NN) row_start[i] = base + incl - d;
}

// Bucket-fill: slot<ELLW -> ELL row, else overflow CSR
__global__ __launch_bounds__(256) void k_fill(const int* __restrict__ ei,
                                              const float* __restrict__ dinv,
                                              int* __restrict__ cur,
                                              int2* __restrict__ ell,
                                              const int* __restrict__ ostart,
                                              int2* __restrict__ ovf) {
  int e = blockIdx.x * 256 + threadIdx.x;
  if (e >= NE) return;
  int s = ei[e];
  int d = ei[NE + e];
  float nrm = dinv[s] * dinv[d];
  int slot = atomicAdd(&cur[d], 1);
  int2 v;
  v.x = s;
  v.y = __builtin_bit_cast(int, nrm);
  if (slot < ELLW) ell[(size_t)d * ELLW + slot] = v;
  else ovf[ostart[d] + slot - ELLW] = v;
}

// Layer-1 GEMM: lin[M,64](bf16) = x[M,128](f32) @ W
__global__ __launch_bounds__(256) void k_gemm_f32(const float* __restrict__ Ain,
                                                  const unsigned short* __restrict__ Wt,
                                                  unsigned short* __restrict__ linbf) {
  constexpr int K = 128, KC = 4, SP = K + 8;
  __shared__ unsigned short Wl[64 * SP];
  int tid = threadIdx.x;
  for (int idx = tid * 8; idx < 64 * K; idx += 2048) {
    int n = idx / K, k = idx % K;
    *(short8*)&Wl[n * SP + k] = *(const short8*)&Wt[idx];
  }
  __syncthreads();

  int lane = tid & 63, wave = tid >> 6;
  int quad = lane >> 4, l16 = lane & 15;

  short8 bfrag[4][KC];
#pragma unroll
  for (int nt = 0; nt < 4; ++nt)
#pragma unroll
    for (int kc = 0; kc < KC; ++kc)
      bfrag[nt][kc] = *(const short8*)&Wl[(nt * 16 + l16) * SP + kc * 32 + quad * 8];

  const int ntiles = NN / 16;  // 31250
  for (int t0 = (blockIdx.x * 4 + wave) * 2; t0 < ntiles; t0 += gridDim.x * 8) {
    floatx4 acc[2][4];
    floatx4 araw[2][KC][2];
#pragma unroll
    for (int tt = 0; tt < 2; ++tt) {
      int arow = (t0 + tt) * 16 + l16;
      const float* Ab = Ain + (size_t)arow * K + quad * 8;
#pragma unroll
      for (int kc = 0; kc < KC; ++kc) {
        araw[tt][kc][0] = *(const floatx4*)(Ab + kc * 32);
        araw[tt][kc][1] = *(const floatx4*)(Ab + kc * 32 + 4);
      }
    }
#pragma unroll
    for (int tt = 0; tt < 2; ++tt) {
      floatx4 z = {0.f, 0.f, 0.f, 0.f};
#pragma unroll
      for (int nt = 0; nt < 4; ++nt) acc[tt][nt] = z;
#pragma unroll
      for (int kc = 0; kc < KC; ++kc) {
        short8 af;
#pragma unroll
        for (int q = 0; q < 4; ++q) {
          af[q] = (short)f2bf(araw[tt][kc][0][q]);
          af[q + 4] = (short)f2bf(araw[tt][kc][1][q]);
        }
#pragma unroll
        for (int nt = 0; nt < 4; ++nt)
          acc[tt][nt] = __builtin_amdgcn_mfma_f32_16x16x32_bf16(af, bfrag[nt][kc], acc[tt][nt], 0, 0, 0);
      }
#pragma unroll
      for (int i = 0; i < 4; ++i) {
        int r = (t0 + tt) * 16 + quad * 4 + i;
        unsigned short* lp = linbf + (size_t)r * 64 + l16;
#pragma unroll
        for (int nt = 0; nt < 4; ++nt) lp[nt * 16] = f2bf(acc[tt][nt][i]);
      }
    }
  }
}

// Layer-1 aggregation (no matvec): h1 = relu(agg(lin1) + b0) -> bf16
// Round-0 gather form: unconditional metadata loads + unconditional pad FMAs
// (pad entries are (self,0)) — maximizes MLP in this latency-bound loop.
__global__ __launch_bounds__(256) void k_agg(const unsigned short* __restrict__ linbf,
                                             const float* __restrict__ dinv,
                                             const float* __restrict__ bias,
                                             const int* __restrict__ deg,
                                             const int2* __restrict__ ell,
                                             const int* __restrict__ ostart,
                                             const int2* __restrict__ ovf,
                                             unsigned short* __restrict__ hout) {
  int r = blockIdx.x * 4 + (threadIdx.x >> 6);
  if (r >= NN) return;
  int c = threadIdx.x & 63;
  const int4* ellv = (const int4*)(ell + (size_t)r * ELLW);
  int4 q0 = ellv[0], q1 = ellv[1], q2 = ellv[2], q3 = ellv[3];
  int dg = deg[r];
  float dv = dinv[r];
  float bc = bias[c];
  float acc = bf2f(linbf[(size_t)r * 64 + c]) * dv * dv;

  acc = fmaf(asf(q0.y), bf2f(linbf[(size_t)q0.x * 64 + c]), acc);
  acc = fmaf(asf(q0.w), bf2f(linbf[(size_t)q0.z * 64 + c]), acc);
  acc = fmaf(asf(q1.y), bf2f(linbf[(size_t)q1.x * 64 + c]), acc);
  acc = fmaf(asf(q1.w), bf2f(linbf[(size_t)q1.z * 64 + c]), acc);
  if (dg > 4) {
    acc = fmaf(asf(q2.y), bf2f(linbf[(size_t)q2.x * 64 + c]), acc);
    acc = fmaf(asf(q2.w), bf2f(linbf[(size_t)q2.z * 64 + c]), acc);
    acc = fmaf(asf(q3.y), bf2f(linbf[(size_t)q3.x * 64 + c]), acc);
    acc = fmaf(asf(q3.w), bf2f(linbf[(size_t)q3.z * 64 + c]), acc);
  }
  if (dg > ELLW) {
    int rs = ostart[r];
    int on = dg - ELLW;
    for (int j = 0; j < on; j += 4) {
      int2 e0 = ovf[rs + j];
      int2 e1 = ovf[rs + j + 1];
      int2 e2 = ovf[rs + j + 2];
      int2 e3 = ovf[rs + j + 3];
      int rem = on - j;
      float n0 = asf(e0.y);
      float n1 = rem > 1 ? asf(e1.y) : 0.f;
      float n2 = rem > 2 ? asf(e2.y) : 0.f;
      float n3 = rem > 3 ? asf(e3.y) : 0.f;
      int s0 = e0.x;
      int s1 = rem > 1 ? e1.x : r;
      int s2 = rem > 2 ? e2.x : r;
      int s3 = rem > 3 ? e3.x : r;
      acc = fmaf(n0, bf2f(linbf[(size_t)s0 * 64 + c]), acc);
      acc = fmaf(n1, bf2f(linbf[(size_t)s1 * 64 + c]), acc);
      acc = fmaf(n2, bf2f(linbf[(size_t)s2 * 64 + c]), acc);
      acc = fmaf(n3, bf2f(linbf[(size_t)s3 * 64 + c]), acc);
    }
  }
  hout[(size_t)r * 64 + c] = f2bf(fmaxf(acc + bc, 0.f));
}

// Fused layer 2/3: hout = relu( agg(hin) @ W + bias ), using agg(h@W) = agg(h)@W.
// POOL=1 (layer 3): skip the H write entirely; block-reduce mean/max per graph
// segment (batch is sorted) in LDS and emit one atomicAdd/atomicMax per (g,feat).
template <int POOL>
__global__ __launch_bounds__(256) void k_layer(const unsigned short* __restrict__ hin,
                                               const float* __restrict__ dinv,
                                               const float* __restrict__ bias,
                                               const int* __restrict__ deg,
                                               const int2* __restrict__ ell,
                                               const int* __restrict__ ostart,
                                               const int2* __restrict__ ovf,
                                               const unsigned short* __restrict__ Wt,  // [n][k] bf16 64x64
                                               unsigned short* __restrict__ hout,
                                               float* __restrict__ gsum,
                                               int* __restrict__ gmax,
                                               int* __restrict__ gcnt,
                                               const int* __restrict__ batch) {
  constexpr int SP = 72;  // bf16 LDS row stride: breaks 128B power-of-2 stride
  // POOL=1 needs a 64x66 f32 staging view (16.9 KB); POOL=0 only the bf16 tile (9.2 KB)
  constexpr int SLDS = POOL ? (64 * 66 * 2) : (64 * SP);
  __shared__ unsigned short Sl[SLDS];
  float* smemf = (float*)Sl;
  int tid = threadIdx.x;
  int lane = tid & 63, wave = tid >> 6, quad = lane >> 4, l16 = lane & 15;

  // stage W flat -> B-frags in regs
  for (int idx = tid * 8; idx < 64 * 64; idx += 2048)
    *(short8*)&Sl[idx] = *(const short8*)&Wt[idx];
  __syncthreads();
  short8 bfrag[4][2];
#pragma unroll
  for (int nt = 0; nt < 4; ++nt)
#pragma unroll
    for (int kc = 0; kc < 2; ++kc)
      bfrag[nt][kc] = *(const short8*)&Sl[(nt * 16 + l16) * 64 + kc * 32 + quad * 8];
  float bb[4];
#pragma unroll
  for (int nt = 0; nt < 4; ++nt) bb[nt] = bias[nt * 16 + l16];
  __syncthreads();  // all waves done reading W before phase 1 overwrites Sl

  int base = blockIdx.x * 64;
  int rbase = base + wave * 16;

  // phase 1: aggregate 16 nodes (wave-wide, lane = feature)
#pragma unroll 4
  for (int j = 0; j < 16; ++j) {
    int r = rbase + j;
    float acc = 0.f;
    if (r < NN) {
      const int4* ellv = (const int4*)(ell + (size_t)r * ELLW);
      int4 q0 = ellv[0], q1 = ellv[1], q2 = ellv[2], q3 = ellv[3];
      int dg = deg[r];
      float dv = dinv[r];
      acc = bf2f(hin[(size_t)r * 64 + lane]) * dv * dv;
      acc = fmaf(asf(q0.y), bf2f(hin[(size_t)q0.x * 64 + lane]), acc);
      acc = fmaf(asf(q0.w), bf2f(hin[(size_t)q0.z * 64 + lane]), acc);
      acc = fmaf(asf(q1.y), bf2f(hin[(size_t)q1.x * 64 + lane]), acc);
      acc = fmaf(asf(q1.w), bf2f(hin[(size_t)q1.z * 64 + lane]), acc);
      if (dg > 4) {
        acc = fmaf(asf(q2.y), bf2f(hin[(size_t)q2.x * 64 + lane]), acc);
        acc = fmaf(asf(q2.w), bf2f(hin[(size_t)q2.z * 64 + lane]), acc);
        acc = fmaf(asf(q3.y), bf2f(hin[(size_t)q3.x * 64 + lane]), acc);
        acc = fmaf(asf(q3.w), bf2f(hin[(size_t)q3.z * 64 + lane]), acc);
      }
      if (dg > ELLW) {
        int rs = ostart[r];
        int on = dg - ELLW;
        for (int jj = 0; jj < on; jj += 4) {
          int2 e0 = ovf[rs + jj];
          int2 e1 = ovf[rs + jj + 1];
          int2 e2 = ovf[rs + jj + 2];
          int2 e3 = ovf[rs + jj + 3];
          int rem = on - jj;
          float n0 = asf(e0.y);
          float n1 = rem > 1 ? asf(e1.y) : 0.f;
          float n2 = rem > 2 ? asf(e2.y) : 0.f;
          float n3 = rem > 3 ? asf(e3.y) : 0.f;
          int s0 = e0.x;
          int s1 = rem > 1 ? e1.x : r;
          int s2 = rem > 2 ? e2.x : r;
          int s3 = rem > 3 ? e3.x : r;
          acc = fmaf(n0, bf2f(hin[(size_t)s0 * 64 + lane]), acc);
          acc = fmaf(n1, bf2f(hin[(size_t)s1 * 64 + lane]), acc);
          acc = fmaf(n2, bf2f(hin[(size_t)s2 * 64 + lane]), acc);
          acc = fmaf(n3, bf2f(hin[(size_t)s3 * 64 + lane]), acc);
        }
      }
    }
    Sl[(wave * 16 + j) * SP + lane] = f2bf(acc);
  }

  // phase 2: s @ W  (wave reads only its own 16 rows -> no barrier needed)
  floatx4 z = {0.f, 0.f, 0.f, 0.f};
  floatx4 acc4[4] = {z, z, z, z};
#pragma unroll
  for (int kc = 0; kc < 2; ++kc) {
    short8 af = *(const short8*)&Sl[(wave * 16 + l16) * SP + kc * 32 + quad * 8];
#pragma unroll
    for (int nt = 0; nt < 4; ++nt)
      acc4[nt] = __builtin_amdgcn_mfma_f32_16x16x32_bf16(af, bfrag[nt][kc], acc4[nt], 0, 0, 0);
  }

  if constexpr (!POOL) {
#pragma unroll
    for (int i = 0; i < 4; ++i) {
      int r = rbase + quad * 4 + i;
      if (r < NN) {
        unsigned short* hp = hout + (size_t)r * 64 + l16;
#pragma unroll
        for (int nt = 0; nt < 4; ++nt)
          hp[nt * 16] = f2bf(fmaxf(acc4[nt][i] + bb[nt], 0.f));
      }
    }
  } else {
    // -------- fused global mean/max pool (layer-3 output never touches HBM) --------
    __shared__ int sb[64];
    __shared__ float reds[256];
    __shared__ float redm[256];
    __shared__ int redc[4];
    __syncthreads();  // all waves done reading their Sl rows before f32 overwrite
#pragma unroll
    for (int i = 0; i < 4; ++i) {
      int row = wave * 16 + quad * 4 + i;
#pragma unroll
      for (int nt = 0; nt < 4; ++nt)
        smemf[row * 66 + nt * 16 + l16] = fmaxf(acc4[nt][i] + bb[nt], 0.f);
    }
    if (tid < 64) sb[tid] = (base + tid < NN) ? batch[base + tid] : 0x7fffffff;
    __syncthreads();
    int nvalid = NN - base; if (nvalid > 64) nvalid = 64;
    int gs = sb[0], ge = sb[nvalid - 1];
    int feat = tid & 63, strip = tid >> 6;
    for (int g = gs; g <= ge; ++g) {   // uniform trip count across block (usually 1)
      float s = 0.f, m = 0.f;
      int cl = 0;
#pragma unroll
      for (int j = 0; j < 16; ++j) {
        int row = strip * 16 + j;
        float v = smemf[row * 66 + feat];
        if (sb[row] == g) { s += v; m = fmaxf(m, v); cl++; }
      }
      reds[tid] = s;
      redm[tid] = m;
      if (feat == 0) redc[strip] = cl;
      __syncthreads();
      if (strip == 0) {
        s += reds[64 + feat] + reds[128 + feat] + reds[192 + feat];
        m = fmaxf(fmaxf(m, redm[64 + feat]), fmaxf(redm[128 + feat], redm[192 + feat]));
        atomicAdd(&gsum[g * 64 + feat], s);
        atomicMax(&gmax[g * 64 + feat], __builtin_bit_cast(int, m));  // v>=0: int order == float order
        if (feat == 0) atomicAdd(&gcnt[g], redc[0] + redc[1] + redc[2] + redc[3]);
      }
      __syncthreads();
    }
  }
}

__global__ __launch_bounds__(128) void k_head(const float* __restrict__ gsum,
                                              const int* __restrict__ gmax,
                                              const int* __restrict__ gcnt,
                                              const float* __restrict__ Wout,
                                              const float* __restrict__ bout,
                                              float* __restrict__ out) {
  __shared__ float p[128];
  int g = blockIdx.x, tid = threadIdx.x;
  if (tid < 64) {
    int c = gcnt[g];
    float inv = c > 0 ? 1.0f / (float)c : 0.f;  // empty graph: sum==0 -> mean 0 matches ref
    p[tid] = gsum[g * 64 + tid] * inv;
    p[64 + tid] = asf(gmax[g * 64 + tid]);      // init 0 matches ref's neginf->0 guard
  }
  __syncthreads();
  if (tid < NC) {
    float acc = bout[tid];
#pragma unroll 8
    for (int c2 = 0; c2 < 128; ++c2) acc += p[c2] * Wout[c2 * NC + tid];
    out[g * NC + tid] = acc;
  }
}

extern "C" void kernel_launch(void* const* d_in, const int* in_sizes, int n_in,
                              void* d_out, int out_size, void* d_ws, size_t ws_size,
                              hipStream_t stream) {
  const float* x     = (const float*)d_in[0];
  const int*   ei    = (const int*)d_in[1];
  const int*   batch = (const int*)d_in[2];
  const float* W0    = (const float*)d_in[3];
  const float* b0    = (const float*)d_in[4];
  const float* W1    = (const float*)d_in[5];
  const float* b1    = (const float*)d_in[6];
  const float* W2    = (const float*)d_in[7];
  const float* b2    = (const float*)d_in[8];
  const float* Wout  = (const float*)d_in[9];
  const float* bout  = (const float*)d_in[10];
  float* out = (float*)d_out;

  char* ws = (char*)d_ws;
  size_t off = 0;
  auto alloc = [&](size_t bytes) -> void* {
    void* p = ws + off;
    off = (off + bytes + 255) & ~(size_t)255;
    return p;
  };
  int*   deg     = (int*)alloc((size_t)NN * 4);
  int*   odeg    = (int*)alloc((size_t)NN * 4);
  int*   counter = (int*)alloc(4);
  float* dinv    = (float*)alloc((size_t)NN * 4);
  int*   ostart  = (int*)alloc((size_t)NN * 4);
  int*   cur     = (int*)alloc((size_t)NN * 4);
  int2*  ell     = (int2*)alloc((size_t)NN * ELLW * 8);   // 32 MB, pad-initialized in k_init
  int2*  ovf     = (int2*)alloc(((size_t)NE + 4) * 8);
  unsigned short* linbf = (unsigned short*)alloc((size_t)NN * 64 * 2);
  unsigned short* H1    = (unsigned short*)alloc((size_t)NN * 64 * 2);
  unsigned short* H2    = (unsigned short*)alloc((size_t)NN * 64 * 2);
  unsigned short* Wt0 = (unsigned short*)alloc(64 * 128 * 2);
  unsigned short* Wt1 = (unsigned short*)alloc(64 * 64 * 2);
  unsigned short* Wt2 = (unsigned short*)alloc(64 * 64 * 2);
  float* gsum = (float*)alloc((size_t)NG * 64 * 4);
  int*   gmax = (int*)alloc((size_t)NG * 64 * 4);
  int*   gcnt = (int*)alloc((size_t)NG * 4);

  // graph prep (merged: zero-init + ELL pad + weight transpose in one launch)
  k_init<<<(NN + 255) / 256, 256, 0, stream>>>(deg, cur, counter, gsum, gmax, gcnt,
                                               (int4*)ell, W0, W1, W2, Wt0, Wt1, Wt2);
  k_deg<<<(NE + 255) / 256, 256, 0, stream>>>(ei + NE, deg);
  k_dinv<<<(NN + 255) / 256, 256, 0, stream>>>(deg, dinv, odeg);
  k_rowstart<<<(NN + 255) / 256, 256, 0, stream>>>(odeg, ostart, counter);
  k_fill<<<(NE + 255) / 256, 256, 0, stream>>>(ei, dinv, cur, ell, ostart, ovf);

  // layer 1: transform-first (x is 128-wide; cheaper to shrink before gathering)
  k_gemm_f32<<<2048, 256, 0, stream>>>(x, Wt0, linbf);
  k_agg<<<(NN + 3) / 4, 256, 0, stream>>>(linbf, dinv, b0, deg, ell, ostart, ovf, H1);
  // layer 2: aggregate-first fused (agg(h)@W + b, relu)
  k_layer<0><<<(NN + 63) / 64, 256, 0, stream>>>(H1, dinv, b1, deg, ell, ostart, ovf, Wt1, H2,
                                                 nullptr, nullptr, nullptr, nullptr);
  // layer 3 + fused mean/max pool (no H3 buffer, no k_pool pass)
  k_layer<1><<<(NN + 63) / 64, 256, 0, stream>>>(H2, dinv, b2, deg, ell, ostart, ovf, Wt2, nullptr,
                                                 gsum, gmax, gcnt, batch);
  k_head<<<NG, 128, 0, stream>>>(gsum, gmax, gcnt, Wout, bout, out);
}

// Round 3
// 775.946 us; speedup vs baseline: 1.3925x; 1.2351x over previous
//
#include <hip/hip_runtime.h>
#include <hip/hip_bf16.h>

#define NN 500000
#define NE 1250000
#define NF 128
#define NH 64
#define NC 10
#define NG 512
#define ELLW 8

typedef __attribute__((ext_vector_type(8))) short short8;
typedef __attribute__((ext_vector_type(4))) float floatx4;

__device__ __forceinline__ unsigned short f2bf(float f) {
  unsigned u = __builtin_bit_cast(unsigned, f);
  u += 0x7FFFu + ((u >> 16) & 1u);
  return (unsigned short)(u >> 16);
}
__device__ __forceinline__ float bf2f(unsigned short u) {
  return __builtin_bit_cast(float, (unsigned)u << 16);
}
__device__ __forceinline__ float asf(int i) { return __builtin_bit_cast(float, i); }

// acc[0..7] += n * bf16x8 row fragment
__device__ __forceinline__ void fma8(float acc[8], float n, short8 v) {
#pragma unroll
  for (int k = 0; k < 8; ++k) acc[k] = fmaf(n, bf2f((unsigned short)v[k]), acc[k]);
}

// merged prep: zero deg/cur/counter/pool-accumulators, pad-init ELL to (self,0),
// transpose-convert all three weights. ELL pad keeps gather loads unconditional
// (round-1 lesson: degree-guarded addresses serialize the latency-bound gather).
__global__ __launch_bounds__(256) void k_init(int* __restrict__ deg, int* __restrict__ cur,
                                              int* __restrict__ counter,
                                              float* __restrict__ gsum, int* __restrict__ gmax,
                                              int* __restrict__ gcnt,
                                              int4* __restrict__ ell4,
                                              const float* __restrict__ W0,
                                              const float* __restrict__ W1,
                                              const float* __restrict__ W2,
                                              unsigned short* __restrict__ Wt0,
                                              unsigned short* __restrict__ Wt1,
                                              unsigned short* __restrict__ Wt2) {
  int i = blockIdx.x * 256 + threadIdx.x;
  if (i < NN) {
    deg[i] = 0; cur[i] = 0;
    int4 p; p.x = i; p.y = 0; p.z = i; p.w = 0;   // two (self, 0) ELL entries
    ell4[(size_t)i * 4 + 0] = p;
    ell4[(size_t)i * 4 + 1] = p;
    ell4[(size_t)i * 4 + 2] = p;
    ell4[(size_t)i * 4 + 3] = p;
  }
  if (i == 0) *counter = 0;
  if (i < NG * 64) { gsum[i] = 0.f; gmax[i] = 0; }
  if (i < NG) gcnt[i] = 0;
  if (i < NF * 64) { int k = i / 64, n = i % 64; Wt0[n * NF + k] = f2bf(W0[i]); }
  if (i < 64 * 64) {
    int k = i / 64, n = i % 64;
    Wt1[n * 64 + k] = f2bf(W1[i]);
    Wt2[n * 64 + k] = f2bf(W2[i]);
  }
}

__global__ __launch_bounds__(256) void k_deg(const int* __restrict__ dst, int* __restrict__ deg) {
  int e = blockIdx.x * 256 + threadIdx.x;
  if (e < NE) atomicAdd(&deg[dst[e]], 1);
}

// merged: dinv + overflow-CSR row starts (wave-scan, one atomic per wave)
__global__ __launch_bounds__(256) void k_dinv_rs(const int* __restrict__ deg,
                                                 float* __restrict__ dinv,
                                                 int* __restrict__ row_start,
                                                 int* __restrict__ counter) {
  int i = blockIdx.x * 256 + threadIdx.x;
  int lane = threadIdx.x & 63;
  int d = 0;
  if (i < NN) {
    d = deg[i];
    dinv[i] = rsqrtf((float)(d + 1));
  }
  int od = d > ELLW ? d - ELLW : 0;
  int incl = od;
#pragma unroll
  for (int off = 1; off < 64; off <<= 1) {
    int n = __shfl_up(incl, off, 64);
    if (lane >= off) incl += n;
  }
  int total = __shfl(incl, 63, 64);
  int base = 0;
  if (lane == 63) base = atomicAdd(counter, total);
  base = __shfl(base, 63, 64);
  if (i < NN) row_start[i] = base + incl - od;
}

// Bucket-fill: slot<ELLW -> ELL row, else overflow CSR
__global__ __launch_bounds__(256) void k_fill(const int* __restrict__ ei,
                                              const float* __restrict__ dinv,
                                              int* __restrict__ cur,
                                              int2* __restrict__ ell,
                                              const int* __restrict__ ostart,
                                              int2* __restrict__ ovf) {
  int e = blockIdx.x * 256 + threadIdx.x;
  if (e >= NE) return;
  int s = ei[e];
  int d = ei[NE + e];
  float nrm = dinv[s] * dinv[d];
  int slot = atomicAdd(&cur[d], 1);
  int2 v;
  v.x = s;
  v.y = __builtin_bit_cast(int, nrm);
  if (slot < ELLW) ell[(size_t)d * ELLW + slot] = v;
  else ovf[ostart[d] + slot - ELLW] = v;
}

// Layer-1 GEMM: lin[M,64](bf16) = x[M,128](f32) @ W
__global__ __launch_bounds__(256) void k_gemm_f32(const float* __restrict__ Ain,
                                                  const unsigned short* __restrict__ Wt,
                                                  unsigned short* __restrict__ linbf) {
  constexpr int K = 128, KC = 4, SP = K + 8;
  __shared__ unsigned short Wl[64 * SP];
  int tid = threadIdx.x;
  for (int idx = tid * 8; idx < 64 * K; idx += 2048) {
    int n = idx / K, k = idx % K;
    *(short8*)&Wl[n * SP + k] = *(const short8*)&Wt[idx];
  }
  __syncthreads();

  int lane = tid & 63, wave = tid >> 6;
  int quad = lane >> 4, l16 = lane & 15;

  short8 bfrag[4][KC];
#pragma unroll
  for (int nt = 0; nt < 4; ++nt)
#pragma unroll
    for (int kc = 0; kc < KC; ++kc)
      bfrag[nt][kc] = *(const short8*)&Wl[(nt * 16 + l16) * SP + kc * 32 + quad * 8];

  const int ntiles = NN / 16;  // 31250
  for (int t0 = (blockIdx.x * 4 + wave) * 2; t0 < ntiles; t0 += gridDim.x * 8) {
    floatx4 acc[2][4];
    floatx4 araw[2][KC][2];
#pragma unroll
    for (int tt = 0; tt < 2; ++tt) {
      int arow = (t0 + tt) * 16 + l16;
      const float* Ab = Ain + (size_t)arow * K + quad * 8;
#pragma unroll
      for (int kc = 0; kc < KC; ++kc) {
        araw[tt][kc][0] = *(const floatx4*)(Ab + kc * 32);
        araw[tt][kc][1] = *(const floatx4*)(Ab + kc * 32 + 4);
      }
    }
#pragma unroll
    for (int tt = 0; tt < 2; ++tt) {
      floatx4 z = {0.f, 0.f, 0.f, 0.f};
#pragma unroll
      for (int nt = 0; nt < 4; ++nt) acc[tt][nt] = z;
#pragma unroll
      for (int kc = 0; kc < KC; ++kc) {
        short8 af;
#pragma unroll
        for (int q = 0; q < 4; ++q) {
          af[q] = (short)f2bf(araw[tt][kc][0][q]);
          af[q + 4] = (short)f2bf(araw[tt][kc][1][q]);
        }
#pragma unroll
        for (int nt = 0; nt < 4; ++nt)
          acc[tt][nt] = __builtin_amdgcn_mfma_f32_16x16x32_bf16(af, bfrag[nt][kc], acc[tt][nt], 0, 0, 0);
      }
#pragma unroll
      for (int i = 0; i < 4; ++i) {
        int r = (t0 + tt) * 16 + quad * 4 + i;
        unsigned short* lp = linbf + (size_t)r * 64 + l16;
#pragma unroll
        for (int nt = 0; nt < 4; ++nt) lp[nt * 16] = f2bf(acc[tt][nt][i]);
      }
    }
  }
}

// Layer-1 aggregation, SoA group-gather form: wave = 8 groups x 8 lanes; each
// group owns one node, each lane 8 features (short8 = 16B). One gather instr
// moves 8 distinct rows -> ~8x MLP vs lane-per-feature form.
__global__ __launch_bounds__(256) void k_agg(const unsigned short* __restrict__ linbf,
                                             const float* __restrict__ dinv,
                                             const float* __restrict__ bias,
                                             const int* __restrict__ deg,
                                             const int2* __restrict__ ell,
                                             const int* __restrict__ ostart,
                                             const int2* __restrict__ ovf,
                                             unsigned short* __restrict__ hout) {
  int tid = threadIdx.x;
  int lane = tid & 63, wave = tid >> 6;
  int g = lane >> 3, sl = lane & 7, fb = sl * 8;
  int r = blockIdx.x * 32 + wave * 8 + g;   // NN % 32 == 0: no tail

  const int4* ellv = (const int4*)(ell + (size_t)r * ELLW);
  int4 q0 = ellv[0], q1 = ellv[1], q2 = ellv[2], q3 = ellv[3];
  int dg = deg[r];
  float dv = dinv[r];
  short8 hs = *(const short8*)&linbf[(size_t)r * 64 + fb];
  short8 g0 = *(const short8*)&linbf[(size_t)q0.x * 64 + fb];
  short8 g1 = *(const short8*)&linbf[(size_t)q0.z * 64 + fb];
  short8 g2 = *(const short8*)&linbf[(size_t)q1.x * 64 + fb];
  short8 g3 = *(const short8*)&linbf[(size_t)q1.z * 64 + fb];
  float acc[8];
  float sw = dv * dv;
#pragma unroll
  for (int k = 0; k < 8; ++k) acc[k] = bf2f((unsigned short)hs[k]) * sw;
  fma8(acc, asf(q0.y), g0);
  fma8(acc, asf(q0.w), g1);
  fma8(acc, asf(q1.y), g2);
  fma8(acc, asf(q1.w), g3);
  if (dg > 4) {   // group-uniform branch
    short8 g4 = *(const short8*)&linbf[(size_t)q2.x * 64 + fb];
    short8 g5 = *(const short8*)&linbf[(size_t)q2.z * 64 + fb];
    short8 g6 = *(const short8*)&linbf[(size_t)q3.x * 64 + fb];
    short8 g7 = *(const short8*)&linbf[(size_t)q3.z * 64 + fb];
    fma8(acc, asf(q2.y), g4);
    fma8(acc, asf(q2.w), g5);
    fma8(acc, asf(q3.y), g6);
    fma8(acc, asf(q3.w), g7);
  }
  if (dg > ELLW) {
    int rs = ostart[r], on = dg - ELLW;
    for (int j = 0; j < on; j += 2) {
      int2 e0 = ovf[rs + j];
      int2 e1 = ovf[rs + j + 1];
      int rem = on - j;
      int sx1 = rem > 1 ? e1.x : r;
      float n1 = rem > 1 ? asf(e1.y) : 0.f;
      short8 f0 = *(const short8*)&linbf[(size_t)e0.x * 64 + fb];
      short8 f1 = *(const short8*)&linbf[(size_t)sx1 * 64 + fb];
      fma8(acc, asf(e0.y), f0);
      fma8(acc, n1, f1);
    }
  }
  floatx4 bv0 = *(const floatx4*)&bias[fb];
  floatx4 bv1 = *(const floatx4*)&bias[fb + 4];
  short8 o;
#pragma unroll
  for (int k = 0; k < 8; ++k) {
    float bk = k < 4 ? bv0[k] : bv1[k - 4];
    o[k] = (short)f2bf(fmaxf(acc[k] + bk, 0.f));
  }
  *(short8*)&hout[(size_t)r * 64 + fb] = o;
}

// Fused layer 2/3: hout = relu( agg(hin) @ W + bias ), using agg(h@W) = agg(h)@W.
// Phase 1 uses the SoA group-gather form (8 nodes per wave-iteration, 2 iterations).
// W stays in its own LDS region; B-frags are read AFTER phase 1 (less VGPR pressure).
// POOL=1 (layer 3): skip the H write; block-reduce mean/max per graph segment.
template <int POOL>
__global__ __launch_bounds__(256) void k_layer(const unsigned short* __restrict__ hin,
                                               const float* __restrict__ dinv,
                                               const float* __restrict__ bias,
                                               const int* __restrict__ deg,
                                               const int2* __restrict__ ell,
                                               const int* __restrict__ ostart,
                                               const int2* __restrict__ ovf,
                                               const unsigned short* __restrict__ Wt,  // [n][k] bf16 64x64
                                               unsigned short* __restrict__ hout,
                                               float* __restrict__ gsum,
                                               int* __restrict__ gmax,
                                               int* __restrict__ gcnt,
                                               const int* __restrict__ batch) {
  constexpr int SP = 72;  // bf16 LDS row stride: breaks 128B power-of-2 stride
  constexpr int SLDS = POOL ? (64 * 66 * 2) : (64 * SP);  // f32 pool view needs 64x66 floats
  __shared__ unsigned short Wl[64 * 64];   // 8 KB, W stays resident
  __shared__ unsigned short Sl[SLDS];
  float* smemf = (float*)Sl;
  int tid = threadIdx.x;
  int lane = tid & 63, wave = tid >> 6, quad = lane >> 4, l16 = lane & 15;
  int g = lane >> 3, sl = lane & 7, fb = sl * 8;

  for (int idx = tid * 8; idx < 64 * 64; idx += 2048)
    *(short8*)&Wl[idx] = *(const short8*)&Wt[idx];

  float bb[4];
#pragma unroll
  for (int nt = 0; nt < 4; ++nt) bb[nt] = bias[nt * 16 + l16];

  int base = blockIdx.x * 64;

  // phase 1: aggregate 16 nodes per wave as 2 iterations x 8 parallel groups
#pragma unroll
  for (int it = 0; it < 2; ++it) {
    int row = wave * 16 + it * 8 + g;
    int r = base + row;
    int rr = r < NN ? r : NN - 1;   // clamp: loads stay unconditional, store guarded
    const int4* ellv = (const int4*)(ell + (size_t)rr * ELLW);
    int4 q0 = ellv[0], q1 = ellv[1], q2 = ellv[2], q3 = ellv[3];
    int dg = deg[rr];
    float dv = dinv[rr];
    short8 hs = *(const short8*)&hin[(size_t)rr * 64 + fb];
    short8 g0 = *(const short8*)&hin[(size_t)q0.x * 64 + fb];
    short8 g1 = *(const short8*)&hin[(size_t)q0.z * 64 + fb];
    short8 g2 = *(const short8*)&hin[(size_t)q1.x * 64 + fb];
    short8 g3 = *(const short8*)&hin[(size_t)q1.z * 64 + fb];
    float acc[8];
    float sw = dv * dv;
#pragma unroll
    for (int k = 0; k < 8; ++k) acc[k] = bf2f((unsigned short)hs[k]) * sw;
    fma8(acc, asf(q0.y), g0);
    fma8(acc, asf(q0.w), g1);
    fma8(acc, asf(q1.y), g2);
    fma8(acc, asf(q1.w), g3);
    if (dg > 4) {
      short8 g4 = *(const short8*)&hin[(size_t)q2.x * 64 + fb];
      short8 g5 = *(const short8*)&hin[(size_t)q2.z * 64 + fb];
      short8 g6 = *(const short8*)&hin[(size_t)q3.x * 64 + fb];
      short8 g7 = *(const short8*)&hin[(size_t)q3.z * 64 + fb];
      fma8(acc, asf(q2.y), g4);
      fma8(acc, asf(q2.w), g5);
      fma8(acc, asf(q3.y), g6);
      fma8(acc, asf(q3.w), g7);
    }
    if (dg > ELLW) {
      int rs = ostart[rr], on = dg - ELLW;
      for (int j = 0; j < on; j += 2) {
        int2 e0 = ovf[rs + j];
        int2 e1 = ovf[rs + j + 1];
        int rem = on - j;
        int sx1 = rem > 1 ? e1.x : rr;
        float n1 = rem > 1 ? asf(e1.y) : 0.f;
        short8 f0 = *(const short8*)&hin[(size_t)e0.x * 64 + fb];
        short8 f1 = *(const short8*)&hin[(size_t)sx1 * 64 + fb];
        fma8(acc, asf(e0.y), f0);
        fma8(acc, n1, f1);
      }
    }
    short8 o;
#pragma unroll
    for (int k = 0; k < 8; ++k) o[k] = (short)f2bf(acc[k]);
    *(short8*)&Sl[row * SP + fb] = o;   // (row*72 + sl*8)*2 bytes: 16B-aligned (144 = 9*16)
  }

  __syncthreads();  // Wl staged (and Sl rows visible for pool epilogue later)

  // B-frags now (after phase 1 -> lower peak VGPR during gather)
  short8 bfrag[4][2];
#pragma unroll
  for (int nt = 0; nt < 4; ++nt)
#pragma unroll
    for (int kc = 0; kc < 2; ++kc)
      bfrag[nt][kc] = *(const short8*)&Wl[(nt * 16 + l16) * 64 + kc * 32 + quad * 8];

  // phase 2: s @ W  (wave reads only its own 16 rows)
  floatx4 z = {0.f, 0.f, 0.f, 0.f};
  floatx4 acc4[4] = {z, z, z, z};
#pragma unroll
  for (int kc = 0; kc < 2; ++kc) {
    short8 af = *(const short8*)&Sl[(wave * 16 + l16) * SP + kc * 32 + quad * 8];
#pragma unroll
    for (int nt = 0; nt < 4; ++nt)
      acc4[nt] = __builtin_amdgcn_mfma_f32_16x16x32_bf16(af, bfrag[nt][kc], acc4[nt], 0, 0, 0);
  }

  if constexpr (!POOL) {
#pragma unroll
    for (int i = 0; i < 4; ++i) {
      int r = base + wave * 16 + quad * 4 + i;
      if (r < NN) {
        unsigned short* hp = hout + (size_t)r * 64 + l16;
#pragma unroll
        for (int nt = 0; nt < 4; ++nt)
          hp[nt * 16] = f2bf(fmaxf(acc4[nt][i] + bb[nt], 0.f));
      }
    }
  } else {
    // -------- fused global mean/max pool (layer-3 output never touches HBM) --------
    __shared__ int sb[64];
    __shared__ float reds[256];
    __shared__ float redm[256];
    __shared__ int redc[4];
    __syncthreads();  // all waves done reading their Sl rows before f32 overwrite
#pragma unroll
    for (int i = 0; i < 4; ++i) {
      int row = wave * 16 + quad * 4 + i;
#pragma unroll
      for (int nt = 0; nt < 4; ++nt)
        smemf[row * 66 + nt * 16 + l16] = fmaxf(acc4[nt][i] + bb[nt], 0.f);
    }
    if (tid < 64) sb[tid] = (base + tid < NN) ? batch[base + tid] : 0x7fffffff;
    __syncthreads();
    int nvalid = NN - base; if (nvalid > 64) nvalid = 64;
    int gs = sb[0], ge = sb[nvalid - 1];
    int feat = tid & 63, strip = tid >> 6;
    for (int gg = gs; gg <= ge; ++gg) {   // uniform trip count across block (usually 1)
      float s = 0.f, m = 0.f;
      int cl = 0;
#pragma unroll
      for (int j = 0; j < 16; ++j) {
        int row = strip * 16 + j;
        float v = smemf[row * 66 + feat];
        if (sb[row] == gg) { s += v; m = fmaxf(m, v); cl++; }
      }
      reds[tid] = s;
      redm[tid] = m;
      if (feat == 0) redc[strip] = cl;
      __syncthreads();
      if (strip == 0) {
        s += reds[64 + feat] + reds[128 + feat] + reds[192 + feat];
        m = fmaxf(fmaxf(m, redm[64 + feat]), fmaxf(redm[128 + feat], redm[192 + feat]));
        atomicAdd(&gsum[gg * 64 + feat], s);
        atomicMax(&gmax[gg * 64 + feat], __builtin_bit_cast(int, m));  // v>=0: int order == float order
        if (feat == 0) atomicAdd(&gcnt[gg], redc[0] + redc[1] + redc[2] + redc[3]);
      }
      __syncthreads();
    }
  }
}

__global__ __launch_bounds__(128) void k_head(const float* __restrict__ gsum,
                                              const int* __restrict__ gmax,
                                              const int* __restrict__ gcnt,
                                              const float* __restrict__ Wout,
                                              const float* __restrict__ bout,
                                              float* __restrict__ out) {
  __shared__ float p[128];
  int g = blockIdx.x, tid = threadIdx.x;
  if (tid < 64) {
    int c = gcnt[g];
    float inv = c > 0 ? 1.0f / (float)c : 0.f;  // empty graph: sum==0 -> mean 0 matches ref
    p[tid] = gsum[g * 64 + tid] * inv;
    p[64 + tid] = asf(gmax[g * 64 + tid]);      // init 0 matches ref's neginf->0 guard
  }
  __syncthreads();
  if (tid < NC) {
    float acc = bout[tid];
#pragma unroll 8
    for (int c2 = 0; c2 < 128; ++c2) acc += p[c2] * Wout[c2 * NC + tid];
    out[g * NC + tid] = acc;
  }
}

extern "C" void kernel_launch(void* const* d_in, const int* in_sizes, int n_in,
                              void* d_out, int out_size, void* d_ws, size_t ws_size,
                              hipStream_t stream) {
  const float* x     = (const float*)d_in[0];
  const int*   ei    = (const int*)d_in[1];
  const int*   batch = (const int*)d_in[2];
  const float* W0    = (const float*)d_in[3];
  const float* b0    = (const float*)d_in[4];
  const float* W1    = (const float*)d_in[5];
  const float* b1    = (const float*)d_in[6];
  const float* W2    = (const float*)d_in[7];
  const float* b2    = (const float*)d_in[8];
  const float* Wout  = (const float*)d_in[9];
  const float* bout  = (const float*)d_in[10];
  float* out = (float*)d_out;

  char* ws = (char*)d_ws;
  size_t off = 0;
  auto alloc = [&](size_t bytes) -> void* {
    void* p = ws + off;
    off = (off + bytes + 255) & ~(size_t)255;
    return p;
  };
  int*   deg     = (int*)alloc((size_t)NN * 4);
  int*   counter = (int*)alloc(4);
  float* dinv    = (float*)alloc((size_t)NN * 4);
  int*   ostart  = (int*)alloc((size_t)NN * 4);
  int*   cur     = (int*)alloc((size_t)NN * 4);
  int2*  ell     = (int2*)alloc((size_t)NN * ELLW * 8);   // 32 MB, pad-initialized in k_init
  int2*  ovf     = (int2*)alloc(((size_t)NE + 4) * 8);
  unsigned short* linbf = (unsigned short*)alloc((size_t)NN * 64 * 2);
  unsigned short* H1    = (unsigned short*)alloc((size_t)NN * 64 * 2);
  unsigned short* H2    = (unsigned short*)alloc((size_t)NN * 64 * 2);
  unsigned short* Wt0 = (unsigned short*)alloc(64 * 128 * 2);
  unsigned short* Wt1 = (unsigned short*)alloc(64 * 64 * 2);
  unsigned short* Wt2 = (unsigned short*)alloc(64 * 64 * 2);
  float* gsum = (float*)alloc((size_t)NG * 64 * 4);
  int*   gmax = (int*)alloc((size_t)NG * 64 * 4);
  int*   gcnt = (int*)alloc((size_t)NG * 4);

  // graph prep (zero-init + ELL pad + weight transpose merged; dinv+rowstart merged)
  k_init<<<(NN + 255) / 256, 256, 0, stream>>>(deg, cur, counter, gsum, gmax, gcnt,
                                               (int4*)ell, W0, W1, W2, Wt0, Wt1, Wt2);
  k_deg<<<(NE + 255) / 256, 256, 0, stream>>>(ei + NE, deg);
  k_dinv_rs<<<(NN + 255) / 256, 256, 0, stream>>>(deg, dinv, ostart, counter);
  k_fill<<<(NE + 255) / 256, 256, 0, stream>>>(ei, dinv, cur, ell, ostart, ovf);

  // layer 1: transform-first (x is 128-wide; cheaper to shrink before gathering)
  k_gemm_f32<<<2048, 256, 0, stream>>>(x, Wt0, linbf);
  k_agg<<<NN / 32, 256, 0, stream>>>(linbf, dinv, b0, deg, ell, ostart, ovf, H1);
  // layer 2: aggregate-first fused (agg(h)@W + b, relu)
  k_layer<0><<<(NN + 63) / 64, 256, 0, stream>>>(H1, dinv, b1, deg, ell, ostart, ovf, Wt1, H2,
                                                 nullptr, nullptr, nullptr, nullptr);
  // layer 3 + fused mean/max pool (no H3 buffer, no k_pool pass)
  k_layer<1><<<(NN + 63) / 64, 256, 0, stream>>>(H2, dinv, b2, deg, ell, ostart, ovf, Wt2, nullptr,
                                                 gsum, gmax, gcnt, batch);
  k_head<<<NG, 128, 0, stream>>>(gsum, gmax, gcnt, Wout, bout, out);
}